// Round 2
// baseline (442.764 us; speedup 1.0000x reference)
//
#include <hip/hip_runtime.h>
#include <stdint.h>

#define B_ 256
#define N_ 256
#define F_ 64
#define H_ 512

typedef _Float16 f16;
typedef _Float16 f16x8 __attribute__((ext_vector_type(8)));
typedef _Float16 f16x4 __attribute__((ext_vector_type(4)));
typedef float    f32x4 __attribute__((ext_vector_type(4)));

__device__ __forceinline__ float sigmoidf_(float x) {
    return 1.0f / (1.0f + __expf(-x));
}

// ---------------------------------------------------------------------------
// k_sums: one pass over z. S = sigmoid(z) (f16), R[b,i] = row sums,
// Cpart[c][b][j] = column partial over this block's 64 rows. grid (4, B_).
__global__ __launch_bounds__(256) void k_sums(const float* __restrict__ z,
                                              f16* __restrict__ S,
                                              float* __restrict__ R,
                                              float* __restrict__ Cpart) {
    int b = blockIdx.y, c = blockIdx.x;
    int tid = threadIdx.x, lane = tid & 63, w = tid >> 6;
    float colacc[4] = {0.f, 0.f, 0.f, 0.f};
    for (int r = 0; r < 16; r++) {
        int i = c * 64 + w * 16 + r;
        size_t base = ((size_t)(b * N_ + i)) * N_;
        float4 v = *(const float4*)(z + base + lane * 4);
        float s0 = sigmoidf_(v.x), s1 = sigmoidf_(v.y),
              s2 = sigmoidf_(v.z), s3 = sigmoidf_(v.w);
        f16x4 sv = { (f16)s0, (f16)s1, (f16)s2, (f16)s3 };
        *(f16x4*)(S + base + lane * 4) = sv;
        colacc[0] += s0; colacc[1] += s1; colacc[2] += s2; colacc[3] += s3;
        float rs = s0 + s1 + s2 + s3;
        for (int off = 32; off; off >>= 1) rs += __shfl_down(rs, off, 64);
        if (lane == 0) R[b * N_ + i] = rs;
    }
    __shared__ float cbuf[4][N_];
    #pragma unroll
    for (int k = 0; k < 4; k++) cbuf[w][lane * 4 + k] = colacc[k];
    __syncthreads();
    float s4 = cbuf[0][tid] + cbuf[1][tid] + cbuf[2][tid] + cbuf[3][tid];
    Cpart[((size_t)c * B_ + b) * N_ + tid] = s4;
}

// ---------------------------------------------------------------------------
// k_norma3: nA[i,j] = (0.5*(S_ij+S_ji)+delta_ij)*Di*Dj, S read exactly once.
// grid (3, B_) x 256.
__global__ __launch_bounds__(256) void k_norma3(const f16* __restrict__ S,
                                                const float* __restrict__ R,
                                                const float* __restrict__ Cpart,
                                                f16* __restrict__ nA) {
    __shared__ f16 T0[128 * 129];
    __shared__ f16 T1[128 * 129];
    __shared__ float Dv[N_];
    int b = blockIdx.y, t = blockIdx.x;
    int tid = threadIdx.x;
    const f16* Sb = S + (size_t)b * N_ * N_;
    f16* Ab = nA + (size_t)b * N_ * N_;

    float cs = Cpart[(size_t)b * N_ + tid]
             + Cpart[((size_t)B_ + b) * N_ + tid]
             + Cpart[((size_t)2 * B_ + b) * N_ + tid]
             + Cpart[((size_t)3 * B_ + b) * N_ + tid];
    Dv[tid] = rsqrtf(1.0f + 1e-6f + 0.5f * (R[b * N_ + tid] + cs));

    auto stage = [&](const f16* src, f16* dst) {
        #pragma unroll
        for (int it = 0; it < 8; it++) {
            int u = it * 256 + tid;
            int r = u >> 4, c8 = (u & 15) * 8;
            *(f16x8*)&dst[r * 129 + c8] = *(const f16x8*)&src[(size_t)r * N_ + c8];
        }
    };
    if (t == 0)      stage(Sb, T0);
    else if (t == 1) stage(Sb + 128 * N_ + 128, T0);
    else           { stage(Sb + 128, T0); stage(Sb + (size_t)128 * N_, T1); }
    __syncthreads();

    auto emit = [&](const f16* Dir, const f16* Mir, int i0, int j0) {
        #pragma unroll
        for (int it = 0; it < 8; it++) {
            int il = it * 16 + (tid >> 4), jl8 = (tid & 15) * 8;
            float di = Dv[i0 + il];
            f16x8 d = *(const f16x8*)&Dir[il * 129 + jl8];
            f16x8 o;
            #pragma unroll
            for (int k = 0; k < 8; k++) {
                float v = 0.5f * ((float)d[k] + (float)Mir[(jl8 + k) * 129 + il]);
                if (i0 + il == j0 + jl8 + k) v += 1.0f;
                o[k] = (f16)(v * di * Dv[j0 + jl8 + k]);
            }
            *(f16x8*)&Ab[(size_t)(i0 + il) * N_ + j0 + jl8] = o;
        }
    };
    if (t == 0)      emit(T0, T0, 0, 0);
    else if (t == 1) emit(T0, T0, 128, 128);
    else           { emit(T0, T1, 0, 128); emit(T1, T0, 128, 0); }
}

// ---------------------------------------------------------------------------
// k_prep: fused weight preprocessing.
// blocks [0,512): XW1t[h,node] = ne[node]·w1[:,h] + b1[h]
// blocks [512,2560): w{2,3}t transpose to f16.
__global__ __launch_bounds__(256) void k_prep(const float* __restrict__ ne,
                                              const float* __restrict__ w1,
                                              const float* __restrict__ b1,
                                              const float* __restrict__ w2,
                                              const float* __restrict__ w3,
                                              f16* __restrict__ XW1t,
                                              f16* __restrict__ w2t,
                                              f16* __restrict__ w3t) {
    int bid = blockIdx.x;
    if (bid < 512) {
        int h = bid, node = threadIdx.x;
        float s = b1[h];
        #pragma unroll 8
        for (int k = 0; k < F_; k++) s += ne[node * F_ + k] * w1[k * H_ + h];
        XW1t[h * N_ + node] = (f16)s;
    } else {
        int idx4 = bid - 512;                    // 0..2047
        int which = idx4 >> 10;                  // 0 -> w2, 1 -> w3
        const float* src = which ? w3 : w2;
        f16* dst = which ? w3t : w2t;
        int idx = (idx4 & 1023) * 256 + threadIdx.x;   // 0..262143
        int k = idx >> 9, n = idx & 511;
        dst[n * H_ + k] = (f16)src[k * H_ + n];
    }
}

// ---------------------------------------------------------------------------
// k_gemm: C(128x128) = A(m,K) @ Bt(n,K)^T. Used only for layer 1 now.
// MODE 0: Out[b][node][512] = relu(acc)
template <int KDIM, int MODE>
__global__ __launch_bounds__(256, 4) void k_gemm(const f16* __restrict__ A, long aBatch,
                                                 const f16* __restrict__ Bt, long bBatch,
                                                 f16* __restrict__ Out,
                                                 const float* __restrict__ bias,
                                                 float* __restrict__ gp) {
    __shared__ f16 As[128 * 64];
    __shared__ f16 Bs[128 * 64];
    const int tid  = threadIdx.x;
    const int lane = tid & 63, wave = tid >> 6;
    const int wm = wave >> 1, wn = wave & 1;

    const int lin = blockIdx.x;
    const int xcd = lin & 7, q = lin >> 3;
    const int n_t = q & 3, p = q >> 2;
    const int grp = xcd * 64 + p;          // 0..511 = (b, m-tile)
    const int b   = grp >> 1, m_t = grp & 1;
    const int m0 = m_t * 128, n0 = n_t * 128;

    const f16* Ab = A + (size_t)b * aBatch;
    const f16* Bb = Bt + (size_t)b * bBatch;

    f32x4 acc[4][4];
    #pragma unroll
    for (int i = 0; i < 4; i++)
        #pragma unroll
        for (int j = 0; j < 4; j++)
            #pragma unroll
            for (int r = 0; r < 4; r++) acc[i][j][r] = 0.0f;

    const int lr = lane >> 3;              // 0..7 row within chunk
    const int kc = (lane & 7) ^ lr;        // global 16B k-chunk to fetch

    const int ln15 = lane & 15;

    for (int kk = 0; kk < KDIM; kk += 64) {
        #pragma unroll
        for (int c = 0; c < 4; c++) {
            int chunk = wave * 4 + c;      // 0..15
            int row = chunk * 8 + lr;      // 0..127
            __builtin_amdgcn_global_load_lds(
                (__attribute__((address_space(1))) void*)(Ab + (size_t)(m0 + row) * KDIM + kk + kc * 8),
                (__attribute__((address_space(3))) void*)(&As[chunk * 512]), 16, 0, 0);
            __builtin_amdgcn_global_load_lds(
                (__attribute__((address_space(1))) void*)(Bb + (size_t)(n0 + row) * KDIM + kk + kc * 8),
                (__attribute__((address_space(3))) void*)(&Bs[chunk * 512]), 16, 0, 0);
        }
        __syncthreads();

        #pragma unroll
        for (int ks = 0; ks < 2; ks++) {
            const int rkc = ks * 4 + (lane >> 4);
            f16x8 aF[4];
            #pragma unroll
            for (int t = 0; t < 4; t++) {
                int ra = wm * 64 + t * 16 + ln15;
                aF[t] = *(const f16x8*)&As[(ra * 8 + (rkc ^ (ra & 7))) * 8];
            }
            #pragma unroll
            for (int h2 = 0; h2 < 2; h2++) {
                f16x8 bF[2];
                #pragma unroll
                for (int t = 0; t < 2; t++) {
                    int rb = wn * 64 + (h2 * 2 + t) * 16 + ln15;
                    bF[t] = *(const f16x8*)&Bs[(rb * 8 + (rkc ^ (rb & 7))) * 8];
                }
                #pragma unroll
                for (int mt = 0; mt < 4; mt++)
                    #pragma unroll
                    for (int t = 0; t < 2; t++)
                        acc[mt][h2 * 2 + t] = __builtin_amdgcn_mfma_f32_16x16x32_f16(aF[mt], bF[t], acc[mt][h2 * 2 + t], 0, 0, 0);
            }
        }
        __syncthreads();
    }

    const int quad = lane >> 4;
    if (MODE == 0) {
        f16* Ob = Out + (size_t)b * (N_ * H_);
        #pragma unroll
        for (int mt = 0; mt < 4; mt++) {
            int node = m0 + wm * 64 + mt * 16 + quad * 4;
            #pragma unroll
            for (int nt = 0; nt < 4; nt++) {
                int h = n0 + wn * 64 + nt * 16 + ln15;
                #pragma unroll
                for (int rr = 0; rr < 4; rr++) {
                    float v = acc[mt][nt][rr];
                    v = v > 0.f ? v : 0.f;
                    Ob[(size_t)(node + rr) * H_ + h] = (f16)v;
                }
            }
        }
    }
}

// ---------------------------------------------------------------------------
// k_fused v2: per (batch b, 128-col h-chunk hc):
//   stage 1: U[j,h] = Hin_b[j,:] @ Wt[hc*128+h,:]^T + bias[h]  (256x128, K=512)
//            A (Hin) staged via global_load_lds dbuf; B (W) read DIRECT
//            global->VGPR with 1-deep register prefetch (L2-resident, shared
//            by 32 batches/XCD) -- no Ws in LDS, stage-1 LDS reads halve.
//   stage 2: relu(nA_b @ U): B (U_t) from LDS (produced locally), A (nA)
//            DIRECT global->VGPR (L2-resident, shared by 4 hc-blocks/XCD).
//            No LDS staging => NO barriers in stage 2; waves free-run.
// T5 setprio around MFMA clusters (phase-split structure => role diversity).
// LDS = As dbuf 64K + U_t 64K = 128K -> 1 block/CU, 8 waves.
template <int REDUCE>
__global__ __launch_bounds__(512, 2) void k_fused(const f16* __restrict__ Hin,
                                                  const f16* __restrict__ Wt,
                                                  const float* __restrict__ bias,
                                                  const f16* __restrict__ nA,
                                                  f16* __restrict__ Hout,
                                                  float* __restrict__ gp) {
    __shared__ f16 As[2][16384];   // 2 x (256 rows x 64 f16) = 64 KB
    __shared__ f16 Ut[32768];      // U^T [128 h][256 j], chunk-swizzled, 64 KB

    const int tid  = threadIdx.x;
    const int lane = tid & 63, wave = tid >> 6;
    const int ln15 = lane & 15, quad = lane >> 4;
    const int wm = wave >> 1, wn = wave & 1;     // wm: m-quadrant(4), wn: n-half(2)

    // XCD grouping: 4 hc-blocks of one batch land on one XCD (share Hin_b, nA_b in L2)
    const int lin = blockIdx.x;
    const int xcd = lin & 7, p = lin >> 3;
    const int grp = xcd * 128 + p;               // 0..1023
    const int b = grp >> 2, hc = grp & 3;

    const f16* Hb = Hin + (size_t)b * (N_ * H_);
    const f16* Ab = nA + (size_t)b * (N_ * N_);
    const f16* Wc = Wt + (size_t)(hc * 128) * H_;

    const int lr = lane >> 3;
    const int kc = (lane & 7) ^ lr;              // swizzled global 16B k-chunk

    // A staging: chunk = 8 rows x 64 f16 = 1 KB; LDS slot s of row r holds chunk s^(r&7)
    auto stageA = [&](int buf, int kt) {
        #pragma unroll
        for (int c = 0; c < 4; c++) {            // Hin: 32 chunks / 8 waves
            int chunk = wave * 4 + c;
            int row = chunk * 8 + lr;            // 0..255
            __builtin_amdgcn_global_load_lds(
                (__attribute__((address_space(1))) void*)(Hb + (size_t)row * H_ + kt * 64 + kc * 8),
                (__attribute__((address_space(3))) void*)(&As[buf][chunk * 512]), 16, 0, 0);
        }
    };
    // direct-global W fragments for one K=64 step: d[ks*4+t]
    auto loadW = [&](f16x8* d, int kt) {
        #pragma unroll
        for (int ks = 0; ks < 2; ks++)
            #pragma unroll
            for (int t = 0; t < 4; t++) {
                int rb = wn * 64 + t * 16 + ln15;          // h row, 0..127
                d[ks * 4 + t] = *(const f16x8*)(Wc + (size_t)rb * H_ + kt * 64 + (ks * 4 + quad) * 8);
            }
    };
    // direct-global nA fragments for one j-tile: d[ks*4+t]
    auto loadA2 = [&](f16x8* d, int jt) {
        #pragma unroll
        for (int ks = 0; ks < 2; ks++)
            #pragma unroll
            for (int t = 0; t < 4; t++) {
                int ra = wm * 64 + t * 16 + ln15;          // i row, 0..255
                d[ks * 4 + t] = *(const f16x8*)(Ab + (size_t)ra * N_ + jt * 64 + (ks * 4 + quad) * 8);
            }
    };

    f32x4 acc[4][4];
    #pragma unroll
    for (int i = 0; i < 4; i++)
        #pragma unroll
        for (int j = 0; j < 4; j++)
            #pragma unroll
            for (int r = 0; r < 4; r++) acc[i][j][r] = 0.0f;

    // ---------------- stage 1: U = Hin @ Wc^T + bias --------------------
    f16x8 bW0[8];
    loadW(bW0, 0);
    stageA(0, 0);
    __syncthreads();                             // prologue drain
    for (int kt = 0; kt < 8; ++kt) {
        const int buf = kt & 1;
        if (kt < 7) stageA(buf ^ 1, kt + 1);
        f16x8 bW1[8];
        if (kt < 7) loadW(bW1, kt + 1);
        __builtin_amdgcn_s_setprio(1);
        #pragma unroll
        for (int ks = 0; ks < 2; ks++) {
            const int rkc = ks * 4 + quad;
            f16x8 aF[4];
            #pragma unroll
            for (int t = 0; t < 4; t++) {
                int ra = wm * 64 + t * 16 + ln15;          // Hin row (j)
                aF[t] = *(const f16x8*)&As[buf][(ra * 8 + (rkc ^ (ra & 7))) * 8];
            }
            #pragma unroll
            for (int mt = 0; mt < 4; mt++)
                #pragma unroll
                for (int nt = 0; nt < 4; nt++)
                    acc[mt][nt] = __builtin_amdgcn_mfma_f32_16x16x32_f16(aF[mt], bW0[ks * 4 + nt], acc[mt][nt], 0, 0, 0);
        }
        __builtin_amdgcn_s_setprio(0);
        if (kt < 7) {
            #pragma unroll
            for (int i = 0; i < 8; i++) bW0[i] = bW1[i];
        }
        __syncthreads();   // drain next-tile loads (hidden under compute) + buf reuse
    }

    // prefetch stage-2 jt=0 A fragments (no LDS involved; latency hides under epilogue)
    f16x8 aN0[8];
    loadA2(aN0, 0);

    // epilogue 1: acc(+bias) -> U_t[h][j] in Ut, chunk-swizzled.
    // C layout: m(j) = wm*64+mt*16+quad*4+rr (4 consecutive j -> f16x4), n(h) = wn*64+nt*16+ln15
    #pragma unroll
    for (int nt = 0; nt < 4; nt++) {
        int hl = wn * 64 + nt * 16 + ln15;
        float bv = bias[hc * 128 + hl];
        #pragma unroll
        for (int mt = 0; mt < 4; mt++) {
            int j = wm * 64 + mt * 16 + quad * 4;
            int slot = (j >> 3) ^ (hl & 7);
            f16x4 v;
            #pragma unroll
            for (int rr = 0; rr < 4; rr++) v[rr] = (f16)(acc[mt][nt][rr] + bv);
            *(f16x4*)&Ut[hl * 256 + slot * 8 + (j & 7)] = v;
        }
    }
    __syncthreads();                             // U_t visible to all waves

    // ---------------- stage 2: relu(nA @ U), barrier-free ----------------
    #pragma unroll
    for (int i = 0; i < 4; i++)
        #pragma unroll
        for (int j = 0; j < 4; j++)
            #pragma unroll
            for (int r = 0; r < 4; r++) acc[i][j][r] = 0.0f;

    for (int jt = 0; jt < 4; ++jt) {
        f16x8 aN1[8];
        if (jt < 3) loadA2(aN1, jt + 1);
        __builtin_amdgcn_s_setprio(1);
        #pragma unroll
        for (int ks = 0; ks < 2; ks++) {
            const int rkc = ks * 4 + quad;
            f16x8 bU[4];
            #pragma unroll
            for (int t = 0; t < 4; t++) {
                int rb = wn * 64 + t * 16 + ln15;          // U_t row (h), 0..127
                int g = jt * 8 + rkc;                      // global 8-f16 chunk in row
                bU[t] = *(const f16x8*)&Ut[rb * 256 + ((g ^ (rb & 7)) * 8)];
            }
            #pragma unroll
            for (int mt = 0; mt < 4; mt++)
                #pragma unroll
                for (int nt = 0; nt < 4; nt++)
                    acc[mt][nt] = __builtin_amdgcn_mfma_f32_16x16x32_f16(aN0[ks * 4 + mt], bU[nt], acc[mt][nt], 0, 0, 0);
        }
        __builtin_amdgcn_s_setprio(0);
        if (jt < 3) {
            #pragma unroll
            for (int i = 0; i < 8; i++) aN0[i] = aN1[i];
        }
    }

    if (REDUCE == 0) {
        f16* Ob = Hout + (size_t)b * (N_ * H_);
        #pragma unroll
        for (int mt = 0; mt < 4; mt++) {
            int node = wm * 64 + mt * 16 + quad * 4;
            #pragma unroll
            for (int nt = 0; nt < 4; nt++) {
                int hg = hc * 128 + wn * 64 + nt * 16 + ln15;
                #pragma unroll
                for (int rr = 0; rr < 4; rr++) {
                    float v = acc[mt][nt][rr];
                    v = v > 0.f ? v : 0.f;
                    Ob[(size_t)(node + rr) * H_ + hg] = (f16)v;
                }
            }
        }
    } else {
        // node-sum readout: this block covers ALL 256 nodes -> gp[b][hc*128 + c]
        float part[4];
        #pragma unroll
        for (int nt = 0; nt < 4; nt++) {
            float s = 0.f;
            #pragma unroll
            for (int mt = 0; mt < 4; mt++)
                #pragma unroll
                for (int rr = 0; rr < 4; rr++) {
                    float v = acc[mt][nt][rr];
                    s += (v > 0.f ? v : 0.f);
                }
            s += __shfl_down(s, 32, 64);
            s += __shfl_down(s, 16, 64);
            part[nt] = s;                        // valid on quad==0 lanes
        }
        __syncthreads();                         // all stage-2 U_t reads done; reuse LDS
        float* red = (float*)&As[0][0];          // 8 waves x 64 cols
        if (quad == 0) {
            #pragma unroll
            for (int nt = 0; nt < 4; nt++)
                red[wave * 64 + nt * 16 + ln15] = part[nt];
        }
        __syncthreads();
        if (tid < 128) {
            int wnl = tid >> 6, cl = tid & 63;
            float g = red[(0 * 2 + wnl) * 64 + cl] + red[(1 * 2 + wnl) * 64 + cl]
                    + red[(2 * 2 + wnl) * 64 + cl] + red[(3 * 2 + wnl) * 64 + cl];
            gp[(size_t)b * H_ + hc * 128 + tid] = g;
        }
    }
}

// ---------------------------------------------------------------------------
// k_logits: logits[b] = (gp[b]/N) @ fcw + fcb.  grid B_ x 256.
__global__ __launch_bounds__(256) void k_logits(const float* __restrict__ gp,
                                                const float* __restrict__ fcw,
                                                const float* __restrict__ fcb,
                                                float* __restrict__ out) {
    int b = blockIdx.x, tid = threadIdx.x;
    const float* g = gp + (size_t)b * H_;
    float g0 = g[tid];
    float g1 = g[tid + 256];
    float p0 = g0 * fcw[tid * 2 + 0] + g1 * fcw[(tid + 256) * 2 + 0];
    float p1 = g0 * fcw[tid * 2 + 1] + g1 * fcw[(tid + 256) * 2 + 1];
    for (int off = 32; off; off >>= 1) {
        p0 += __shfl_down(p0, off, 64);
        p1 += __shfl_down(p1, off, 64);
    }
    __shared__ float r0[4], r1[4];
    int lane = tid & 63, w = tid >> 6;
    if (lane == 0) { r0[w] = p0; r1[w] = p1; }
    __syncthreads();
    const float inv = 1.0f / N_;
    if (tid == 0) out[b * 2 + 0] = (r0[0] + r0[1] + r0[2] + r0[3]) * inv + fcb[0];
    if (tid == 1) out[b * 2 + 1] = (r1[0] + r1[1] + r1[2] + r1[3]) * inv + fcb[1];
}

// ---------------------------------------------------------------------------
extern "C" void kernel_launch(void* const* d_in, const int* in_sizes, int n_in,
                              void* d_out, int out_size, void* d_ws, size_t ws_size,
                              hipStream_t stream) {
    const float* z   = (const float*)d_in[0];
    const float* ne  = (const float*)d_in[1];
    const float* w1  = (const float*)d_in[2];
    const float* b1  = (const float*)d_in[3];
    const float* w2  = (const float*)d_in[4];
    const float* b2  = (const float*)d_in[5];
    const float* w3  = (const float*)d_in[6];
    const float* b3  = (const float*)d_in[7];
    const float* fcw = (const float*)d_in[8];
    const float* fcb = (const float*)d_in[9];
    float* out = (float*)d_out;

    char* ws = (char*)d_ws;
    f16*   T     = (f16*)(ws + 0);            // 67,108,864 (H2 in fused pipeline)
    float* R     = (float*)(ws + 0);          //    262,144 (alias T, dead after norma3)
    float* Cpart = (float*)(ws + 262144);     //  1,048,576 (alias T, dead after norma3)
    f16*   nA    = (f16*)(ws + 67108864);     // 33,554,432
    f16*   Hh    = (f16*)(ws + 100663296);    // 67,108,864 (H1)
    f16*   S     = (f16*)(ws + 100663296);    // 33,554,432 (alias Hh, dead after norma3)
    float* gpart = (float*)(ws + 100663296);  //    524,288 (alias Hh, H1 dead after F2)
    f16*   XW1t  = (f16*)(ws + 167772160);    //    262,144
    f16*   w2t   = (f16*)(ws + 168034304);    //    524,288
    f16*   w3t   = (f16*)(ws + 168558592);    //    524,288

    k_sums  <<<dim3(4, B_), 256, 0, stream>>>(z, S, R, Cpart);
    k_norma3<<<dim3(3, B_), 256, 0, stream>>>(S, R, Cpart, nA);
    k_prep  <<<2560,        256, 0, stream>>>(ne, w1, b1, w2, w3, XW1t, w2t, w3t);

    // Layer 1: H1 = relu(nA @ XW1)
    k_gemm<256, 0><<<2048, 256, 0, stream>>>(nA, 65536, XW1t, 0, Hh, nullptr, nullptr);
    // Layer 2 fused: H2 = relu(nA @ (H1 @ w2 + b2))   (U never touches HBM)
    k_fused<0><<<1024, 512, 0, stream>>>(Hh, w2t, b2, nA, T, nullptr);
    // Layer 3 fused + readout: gp[b][h] = sum_i relu(nA @ (H2 @ w3 + b3))[i][h]
    k_fused<1><<<1024, 512, 0, stream>>>(T, w3t, b3, nA, nullptr, gpart);

    k_logits<<<B_, 256, 0, stream>>>(gpart, fcw, fcb, out);
}

// Round 4
// 315.052 us; speedup vs baseline: 1.4054x; 1.4054x over previous
//
#include <hip/hip_runtime.h>
#include <stdint.h>

#define B_ 256
#define N_ 256
#define F_ 64
#define H_ 512

typedef _Float16 f16;
typedef _Float16 f16x8 __attribute__((ext_vector_type(8)));
typedef _Float16 f16x4 __attribute__((ext_vector_type(4)));
typedef _Float16 f16x2 __attribute__((ext_vector_type(2)));
typedef float    f32x4 __attribute__((ext_vector_type(4)));

__device__ __forceinline__ float sigmoidf_(float x) {
    return 1.0f / (1.0f + __expf(-x));
}

// ---------------------------------------------------------------------------
// k_fsum: fused sigmoid + symmetrize + degree-normalize, one block per batch.
// S = sigmoid(z_b) lives ONLY in LDS (256 x LD f16); row sums via shuffle,
// col sums via per-lane partials + cross-wave LDS reduce; then
// nA[i,j] = (0.5*(S_ij+S_ji)+delta_ij)*Di*Dj emitted straight to global.
// HBM traffic: read z (64 MB) + write nA (32 MB); S round-trip eliminated.
// LD=258: rows are 516 B (4B-aligned only!) -> ALL LDS accesses to T must be
// <=4B-wide (f16x2/f16 scalar). ds_read_b128 here faulted in round 3.
// Transpose column reads: row stride 1032 dwords == 8 mod 32 -> 8-way
// conflict (~2.9x on those reads) -- acceptable, emit is a small fraction.
__global__ __launch_bounds__(512) void k_fsum(const float* __restrict__ z,
                                              f16* __restrict__ nA) {
    constexpr int LD = 258;
    __shared__ f16 T[256 * LD];          // 132,096 B
    __shared__ float cpart[8][256];      // 8 KB
    __shared__ float rbuf[256];
    __shared__ float Dv[256];

    const int b = blockIdx.x;
    const int tid = threadIdx.x, lane = tid & 63, w = tid >> 6;
    const float* zb = z + (size_t)b * (N_ * N_);

    float colacc[4] = {0.f, 0.f, 0.f, 0.f};
    for (int r = 0; r < 32; r++) {
        int i = w * 32 + r;
        float4 v = *(const float4*)(zb + (size_t)i * N_ + lane * 4);
        float s0 = sigmoidf_(v.x), s1 = sigmoidf_(v.y),
              s2 = sigmoidf_(v.z), s3 = sigmoidf_(v.w);
        f16x2 p0 = { (f16)s0, (f16)s1 }, p1 = { (f16)s2, (f16)s3 };
        *(f16x2*)&T[i * LD + lane * 4]     = p0;   // byte 516*i + 8*lane: 4B-aligned
        *(f16x2*)&T[i * LD + lane * 4 + 2] = p1;
        colacc[0] += s0; colacc[1] += s1; colacc[2] += s2; colacc[3] += s3;
        float rs = s0 + s1 + s2 + s3;
        for (int off = 32; off; off >>= 1) rs += __shfl_down(rs, off, 64);
        if (lane == 0) rbuf[i] = rs;
    }
    #pragma unroll
    for (int k = 0; k < 4; k++) cpart[w][lane * 4 + k] = colacc[k];
    __syncthreads();

    if (tid < 256) {
        float cs = 0.f;
        #pragma unroll
        for (int ww = 0; ww < 8; ww++) cs += cpart[ww][tid];
        Dv[tid] = rsqrtf(1.0f + 1e-6f + 0.5f * (rbuf[tid] + cs));
    }
    __syncthreads();

    // emit: each thread owns column-chunk j8 = (tid&31)*8 across 16 rows.
    const int j8 = (tid & 31) * 8;
    float dj[8];
    #pragma unroll
    for (int k = 0; k < 8; k++) dj[k] = Dv[j8 + k];
    f16* Ob = nA + (size_t)b * (N_ * N_);
    for (int it = 0; it < 16; it++) {
        int i = it * 16 + (tid >> 5);
        float di = Dv[i];
        // direct row read as 4 x f16x2 (4B-aligned; b128 would fault on odd i)
        f16x2 dd[4];
        #pragma unroll
        for (int c = 0; c < 4; c++)
            dd[c] = *(const f16x2*)&T[i * LD + j8 + c * 2];
        f16x8 o;
        #pragma unroll
        for (int k = 0; k < 8; k++) {
            float sij = (float)dd[k >> 1][k & 1];
            float v = 0.5f * (sij + (float)T[(j8 + k) * LD + i]);
            if (i == j8 + k) v += 1.0f;
            o[k] = (f16)(v * di * dj[k]);
        }
        *(f16x8*)&Ob[(size_t)i * N_ + j8] = o;     // global 16B store, aligned
    }
}

// ---------------------------------------------------------------------------
// k_prep: fused weight preprocessing.
// blocks [0,512): XW1t[h,node] = ne[node]·w1[:,h] + b1[h]
// blocks [512,2560): w{2,3}t transpose to f16.
__global__ __launch_bounds__(256) void k_prep(const float* __restrict__ ne,
                                              const float* __restrict__ w1,
                                              const float* __restrict__ b1,
                                              const float* __restrict__ w2,
                                              const float* __restrict__ w3,
                                              f16* __restrict__ XW1t,
                                              f16* __restrict__ w2t,
                                              f16* __restrict__ w3t) {
    int bid = blockIdx.x;
    if (bid < 512) {
        int h = bid, node = threadIdx.x;
        float s = b1[h];
        #pragma unroll 8
        for (int k = 0; k < F_; k++) s += ne[node * F_ + k] * w1[k * H_ + h];
        XW1t[h * N_ + node] = (f16)s;
    } else {
        int idx4 = bid - 512;                    // 0..2047
        int which = idx4 >> 10;                  // 0 -> w2, 1 -> w3
        const float* src = which ? w3 : w2;
        f16* dst = which ? w3t : w2t;
        int idx = (idx4 & 1023) * 256 + threadIdx.x;   // 0..262143
        int k = idx >> 9, n = idx & 511;
        dst[n * H_ + k] = (f16)src[k * H_ + n];
    }
}

// ---------------------------------------------------------------------------
// k_gemm: C(128x128) = A(m,K) @ Bt(n,K)^T. Used only for layer 1 now.
// MODE 0: Out[b][node][512] = relu(acc)
template <int KDIM, int MODE>
__global__ __launch_bounds__(256, 4) void k_gemm(const f16* __restrict__ A, long aBatch,
                                                 const f16* __restrict__ Bt, long bBatch,
                                                 f16* __restrict__ Out,
                                                 const float* __restrict__ bias,
                                                 float* __restrict__ gp) {
    __shared__ f16 As[128 * 64];
    __shared__ f16 Bs[128 * 64];
    const int tid  = threadIdx.x;
    const int lane = tid & 63, wave = tid >> 6;
    const int wm = wave >> 1, wn = wave & 1;

    const int lin = blockIdx.x;
    const int xcd = lin & 7, q = lin >> 3;
    const int n_t = q & 3, p = q >> 2;
    const int grp = xcd * 64 + p;          // 0..511 = (b, m-tile)
    const int b   = grp >> 1, m_t = grp & 1;
    const int m0 = m_t * 128, n0 = n_t * 128;

    const f16* Ab = A + (size_t)b * aBatch;
    const f16* Bb = Bt + (size_t)b * bBatch;

    f32x4 acc[4][4];
    #pragma unroll
    for (int i = 0; i < 4; i++)
        #pragma unroll
        for (int j = 0; j < 4; j++)
            #pragma unroll
            for (int r = 0; r < 4; r++) acc[i][j][r] = 0.0f;

    const int lr = lane >> 3;              // 0..7 row within chunk
    const int kc = (lane & 7) ^ lr;        // global 16B k-chunk to fetch

    const int ln15 = lane & 15;

    for (int kk = 0; kk < KDIM; kk += 64) {
        #pragma unroll
        for (int c = 0; c < 4; c++) {
            int chunk = wave * 4 + c;      // 0..15
            int row = chunk * 8 + lr;      // 0..127
            __builtin_amdgcn_global_load_lds(
                (__attribute__((address_space(1))) void*)(Ab + (size_t)(m0 + row) * KDIM + kk + kc * 8),
                (__attribute__((address_space(3))) void*)(&As[chunk * 512]), 16, 0, 0);
            __builtin_amdgcn_global_load_lds(
                (__attribute__((address_space(1))) void*)(Bb + (size_t)(n0 + row) * KDIM + kk + kc * 8),
                (__attribute__((address_space(3))) void*)(&Bs[chunk * 512]), 16, 0, 0);
        }
        __syncthreads();

        #pragma unroll
        for (int ks = 0; ks < 2; ks++) {
            const int rkc = ks * 4 + (lane >> 4);
            f16x8 aF[4];
            #pragma unroll
            for (int t = 0; t < 4; t++) {
                int ra = wm * 64 + t * 16 + ln15;
                aF[t] = *(const f16x8*)&As[(ra * 8 + (rkc ^ (ra & 7))) * 8];
            }
            #pragma unroll
            for (int h2 = 0; h2 < 2; h2++) {
                f16x8 bF[2];
                #pragma unroll
                for (int t = 0; t < 2; t++) {
                    int rb = wn * 64 + (h2 * 2 + t) * 16 + ln15;
                    bF[t] = *(const f16x8*)&Bs[(rb * 8 + (rkc ^ (rb & 7))) * 8];
                }
                #pragma unroll
                for (int mt = 0; mt < 4; mt++)
                    #pragma unroll
                    for (int t = 0; t < 2; t++)
                        acc[mt][h2 * 2 + t] = __builtin_amdgcn_mfma_f32_16x16x32_f16(aF[mt], bF[t], acc[mt][h2 * 2 + t], 0, 0, 0);
            }
        }
        __syncthreads();
    }

    const int quad = lane >> 4;
    if (MODE == 0) {
        f16* Ob = Out + (size_t)b * (N_ * H_);
        #pragma unroll
        for (int mt = 0; mt < 4; mt++) {
            int node = m0 + wm * 64 + mt * 16 + quad * 4;
            #pragma unroll
            for (int nt = 0; nt < 4; nt++) {
                int h = n0 + wn * 64 + nt * 16 + ln15;
                #pragma unroll
                for (int rr = 0; rr < 4; rr++) {
                    float v = acc[mt][nt][rr];
                    v = v > 0.f ? v : 0.f;
                    Ob[(size_t)(node + rr) * H_ + h] = (f16)v;
                }
            }
        }
    }
}

// ---------------------------------------------------------------------------
// k_fused (round-1 proven version): per (batch b, 128-col h-chunk hc):
//   stage 1: U[j,h] = Hin_b[j,:] @ Wt[hc*128+h,:]^T + bias[h]   (256x128, K=512)
//            -> kept in LDS as U_t[h][j] (f16, XOR-chunk swizzled)
//   stage 2: relu(nA_b @ U)  (256x128, K=256), B-operand straight from LDS.
// REDUCE=0: write Hout[b][node][512] node-major.
// REDUCE=1: node-sum readout -> gp[b][512].
template <int REDUCE>
__global__ __launch_bounds__(512, 2) void k_fused(const f16* __restrict__ Hin,
                                                  const f16* __restrict__ Wt,
                                                  const float* __restrict__ bias,
                                                  const f16* __restrict__ nA,
                                                  f16* __restrict__ Hout,
                                                  float* __restrict__ gp) {
    __shared__ f16 As[2][16384];   // 2 x (256 rows x 64 f16) = 64 KB
    __shared__ f16 WU[32768];      // stage1: Ws[2][8192] (2x16KB); stage2: U_t 128x256

    const int tid  = threadIdx.x;
    const int lane = tid & 63, wave = tid >> 6;
    const int ln15 = lane & 15, quad = lane >> 4;
    const int wm = wave >> 1, wn = wave & 1;     // wm: m-quadrant(4), wn: n-half(2)

    // XCD grouping: 4 hc-blocks of one batch land on one XCD (share Hin_b, nA_b in L2)
    const int lin = blockIdx.x;
    const int xcd = lin & 7, p = lin >> 3;
    const int grp = xcd * 128 + p;               // 0..1023
    const int b = grp >> 2, hc = grp & 3;

    const f16* Hb = Hin + (size_t)b * (N_ * H_);
    const f16* Ab = nA + (size_t)b * (N_ * N_);
    const f16* Wc = Wt + (size_t)(hc * 128) * H_;

    const int lr = lane >> 3;
    const int kc = (lane & 7) ^ lr;              // swizzled global 16B k-chunk

    // loaders: chunk = 8 rows x 64 f16 = 1 KB; LDS slot s of row r holds global chunk s^(r&7)
    auto stage1 = [&](int buf, int kt) {
        #pragma unroll
        for (int c = 0; c < 4; c++) {            // Hin: 32 chunks / 8 waves
            int chunk = wave * 4 + c;
            int row = chunk * 8 + lr;            // 0..255
            __builtin_amdgcn_global_load_lds(
                (__attribute__((address_space(1))) void*)(Hb + (size_t)row * H_ + kt * 64 + kc * 8),
                (__attribute__((address_space(3))) void*)(&As[buf][chunk * 512]), 16, 0, 0);
        }
        #pragma unroll
        for (int c = 0; c < 2; c++) {            // Wt: 16 chunks / 8 waves
            int chunk = wave * 2 + c;
            int row = chunk * 8 + lr;            // 0..127
            __builtin_amdgcn_global_load_lds(
                (__attribute__((address_space(1))) void*)(Wc + (size_t)row * H_ + kt * 64 + kc * 8),
                (__attribute__((address_space(3))) void*)(&WU[buf * 8192 + chunk * 512]), 16, 0, 0);
        }
    };
    auto stage2 = [&](int buf, int jt) {
        #pragma unroll
        for (int c = 0; c < 4; c++) {            // nA: 32 chunks / 8 waves
            int chunk = wave * 4 + c;
            int row = chunk * 8 + lr;
            __builtin_amdgcn_global_load_lds(
                (__attribute__((address_space(1))) void*)(Ab + (size_t)row * N_ + jt * 64 + kc * 8),
                (__attribute__((address_space(3))) void*)(&As[buf][chunk * 512]), 16, 0, 0);
        }
    };

    f32x4 acc[4][4];
    #pragma unroll
    for (int i = 0; i < 4; i++)
        #pragma unroll
        for (int j = 0; j < 4; j++)
            #pragma unroll
            for (int r = 0; r < 4; r++) acc[i][j][r] = 0.0f;

    // ---------------- stage 1: U = Hin @ Wc^T + bias --------------------
    stage1(0, 0);
    __syncthreads();                             // prologue drain (latency exposed once)
    for (int kt = 0; kt < 8; ++kt) {
        if (kt < 7) stage1((kt + 1) & 1, kt + 1);
        else        stage2(0, 0);                // prefetch first nA tile into buf0
        const int buf = kt & 1;
        #pragma unroll
        for (int ks = 0; ks < 2; ks++) {
            const int rkc = ks * 4 + quad;
            f16x8 aF[4], bF[4];
            #pragma unroll
            for (int t = 0; t < 4; t++) {
                int ra = wm * 64 + t * 16 + ln15;          // Hin row (j)
                aF[t] = *(const f16x8*)&As[buf][(ra * 8 + (rkc ^ (ra & 7))) * 8];
            }
            #pragma unroll
            for (int t = 0; t < 4; t++) {
                int rb = wn * 64 + t * 16 + ln15;          // Wt row (h), 0..127
                bF[t] = *(const f16x8*)&WU[buf * 8192 + (rb * 8 + (rkc ^ (rb & 7))) * 8];
            }
            #pragma unroll
            for (int mt = 0; mt < 4; mt++)
                #pragma unroll
                for (int nt = 0; nt < 4; nt++)
                    acc[mt][nt] = __builtin_amdgcn_mfma_f32_16x16x32_f16(aF[mt], bF[nt], acc[mt][nt], 0, 0, 0);
        }
        __syncthreads();   // drain next-tile loads (hidden under MFMA) + protect buf reuse
    }

    // epilogue 1: acc(+bias) -> U_t[h][j] in WU, chunk-swizzled.
    // C layout: m(j) = wm*64+mt*16+quad*4+rr (4 consecutive j -> f16x4), n(h) = wn*64+nt*16+ln15
    #pragma unroll
    for (int nt = 0; nt < 4; nt++) {
        int hl = wn * 64 + nt * 16 + ln15;
        float bv = bias[hc * 128 + hl];
        #pragma unroll
        for (int mt = 0; mt < 4; mt++) {
            int j = wm * 64 + mt * 16 + quad * 4;
            int slot = (j >> 3) ^ (hl & 7);
            f16x4 v;
            #pragma unroll
            for (int rr = 0; rr < 4; rr++) v[rr] = (f16)(acc[mt][nt][rr] + bv);
            *(f16x4*)&WU[hl * 256 + slot * 8 + (j & 7)] = v;
        }
    }
    __syncthreads();                             // U_t visible to all waves

    // ---------------- stage 2: relu(nA @ U) -----------------------------
    #pragma unroll
    for (int i = 0; i < 4; i++)
        #pragma unroll
        for (int j = 0; j < 4; j++)
            #pragma unroll
            for (int r = 0; r < 4; r++) acc[i][j][r] = 0.0f;

    for (int jt = 0; jt < 4; ++jt) {
        if (jt < 3) stage2((jt + 1) & 1, jt + 1);
        const int buf = jt & 1;
        #pragma unroll
        for (int ks = 0; ks < 2; ks++) {
            const int rkc = ks * 4 + quad;
            f16x8 aF[4], bF[4];
            #pragma unroll
            for (int t = 0; t < 4; t++) {
                int ra = wm * 64 + t * 16 + ln15;          // nA row (i)
                aF[t] = *(const f16x8*)&As[buf][(ra * 8 + (rkc ^ (ra & 7))) * 8];
            }
            #pragma unroll
            for (int t = 0; t < 4; t++) {
                int rb = wn * 64 + t * 16 + ln15;          // U_t row (h), 0..127
                int g = jt * 8 + rkc;                      // global 8-f16 chunk in row
                bF[t] = *(const f16x8*)&WU[rb * 256 + ((g ^ (rb & 7)) * 8)];
            }
            #pragma unroll
            for (int mt = 0; mt < 4; mt++)
                #pragma unroll
                for (int nt = 0; nt < 4; nt++)
                    acc[mt][nt] = __builtin_amdgcn_mfma_f32_16x16x32_f16(aF[mt], bF[nt], acc[mt][nt], 0, 0, 0);
        }
        __syncthreads();
    }

    if (REDUCE == 0) {
        f16* Ob = Hout + (size_t)b * (N_ * H_);
        #pragma unroll
        for (int mt = 0; mt < 4; mt++) {
            int node = wm * 64 + mt * 16 + quad * 4;
            #pragma unroll
            for (int nt = 0; nt < 4; nt++) {
                int hg = hc * 128 + wn * 64 + nt * 16 + ln15;
                #pragma unroll
                for (int rr = 0; rr < 4; rr++) {
                    float v = acc[mt][nt][rr];
                    v = v > 0.f ? v : 0.f;
                    Ob[(size_t)(node + rr) * H_ + hg] = (f16)v;
                }
            }
        }
    } else {
        // node-sum readout: this block covers ALL 256 nodes -> gp[b][hc*128 + c]
        float part[4];
        #pragma unroll
        for (int nt = 0; nt < 4; nt++) {
            float s = 0.f;
            #pragma unroll
            for (int mt = 0; mt < 4; mt++)
                #pragma unroll
                for (int rr = 0; rr < 4; rr++) {
                    float v = acc[mt][nt][rr];
                    s += (v > 0.f ? v : 0.f);
                }
            s += __shfl_down(s, 32, 64);
            s += __shfl_down(s, 16, 64);
            part[nt] = s;                        // valid on quad==0 lanes
        }
        __syncthreads();                         // LDS dead; reuse As as float scratch
        float* red = (float*)&As[0][0];          // 8 waves x 64 cols
        if (quad == 0) {
            #pragma unroll
            for (int nt = 0; nt < 4; nt++)
                red[wave * 64 + nt * 16 + ln15] = part[nt];
        }
        __syncthreads();
        if (tid < 128) {
            int wnl = tid >> 6, cl = tid & 63;
            float g = red[(0 * 2 + wnl) * 64 + cl] + red[(1 * 2 + wnl) * 64 + cl]
                    + red[(2 * 2 + wnl) * 64 + cl] + red[(3 * 2 + wnl) * 64 + cl];
            gp[(size_t)b * H_ + hc * 128 + tid] = g;
        }
    }
}

// ---------------------------------------------------------------------------
// k_logits: logits[b] = (gp[b]/N) @ fcw + fcb.  grid B_ x 256.
__global__ __launch_bounds__(256) void k_logits(const float* __restrict__ gp,
                                                const float* __restrict__ fcw,
                                                const float* __restrict__ fcb,
                                                float* __restrict__ out) {
    int b = blockIdx.x, tid = threadIdx.x;
    const float* g = gp + (size_t)b * H_;
    float g0 = g[tid];
    float g1 = g[tid + 256];
    float p0 = g0 * fcw[tid * 2 + 0] + g1 * fcw[(tid + 256) * 2 + 0];
    float p1 = g0 * fcw[tid * 2 + 1] + g1 * fcw[(tid + 256) * 2 + 1];
    for (int off = 32; off; off >>= 1) {
        p0 += __shfl_down(p0, off, 64);
        p1 += __shfl_down(p1, off, 64);
    }
    __shared__ float r0[4], r1[4];
    int lane = tid & 63, w = tid >> 6;
    if (lane == 0) { r0[w] = p0; r1[w] = p1; }
    __syncthreads();
    const float inv = 1.0f / N_;
    if (tid == 0) out[b * 2 + 0] = (r0[0] + r0[1] + r0[2] + r0[3]) * inv + fcb[0];
    if (tid == 1) out[b * 2 + 1] = (r1[0] + r1[1] + r1[2] + r1[3]) * inv + fcb[1];
}

// ---------------------------------------------------------------------------
extern "C" void kernel_launch(void* const* d_in, const int* in_sizes, int n_in,
                              void* d_out, int out_size, void* d_ws, size_t ws_size,
                              hipStream_t stream) {
    const float* z   = (const float*)d_in[0];
    const float* ne  = (const float*)d_in[1];
    const float* w1  = (const float*)d_in[2];
    const float* b1  = (const float*)d_in[3];
    const float* w2  = (const float*)d_in[4];
    const float* b2  = (const float*)d_in[5];
    const float* w3  = (const float*)d_in[6];
    const float* b3  = (const float*)d_in[7];
    const float* fcw = (const float*)d_in[8];
    const float* fcb = (const float*)d_in[9];
    float* out = (float*)d_out;

    char* ws = (char*)d_ws;
    f16*   T     = (f16*)(ws + 0);            // 67,108,864 (T2/T3 intermediate)
    f16*   nA    = (f16*)(ws + 67108864);     // 33,554,432
    f16*   Hh    = (f16*)(ws + 100663296);    // 67,108,864 (H1)
    float* gpart = (float*)(ws + 100663296);  //    524,288 (alias Hh, H1 dead after F2)
    f16*   XW1t  = (f16*)(ws + 167772160);    //    262,144
    f16*   w2t   = (f16*)(ws + 168034304);    //    524,288
    f16*   w3t   = (f16*)(ws + 168558592);    //    524,288

    // Fused sigmoid/symmetrize/normalize: z -> nA directly (S never hits HBM)
    k_fsum<<<256, 512, 0, stream>>>(z, nA);
    k_prep<<<2560, 256, 0, stream>>>(ne, w1, b1, w2, w3, XW1t, w2t, w3t);

    // Layer 1: H1 = relu(nA @ XW1)
    k_gemm<256, 0><<<2048, 256, 0, stream>>>(nA, 65536, XW1t, 0, Hh, nullptr, nullptr);
    // Layer 2 fused: H2 = relu(nA @ (H1 @ w2 + b2))   (U never touches HBM)
    k_fused<0><<<1024, 512, 0, stream>>>(Hh, w2t, b2, nA, T, nullptr);
    // Layer 3 fused + readout: gp[b][h] = sum_i relu(nA @ (H2 @ w3 + b3))[i][h]
    k_fused<1><<<1024, 512, 0, stream>>>(T, w3t, b3, nA, nullptr, gpart);

    k_logits<<<B_, 256, 0, stream>>>(gpart, fcw, fcb, out);
}

// Round 5
// 308.033 us; speedup vs baseline: 1.4374x; 1.0228x over previous
//
#include <hip/hip_runtime.h>
#include <stdint.h>

#define B_ 256
#define N_ 256
#define F_ 64
#define H_ 512

typedef _Float16 f16;
typedef _Float16 f16x8 __attribute__((ext_vector_type(8)));
typedef _Float16 f16x4 __attribute__((ext_vector_type(4)));
typedef _Float16 f16x2 __attribute__((ext_vector_type(2)));
typedef float    f32x4 __attribute__((ext_vector_type(4)));

__device__ __forceinline__ float sigmoidf_(float x) {
    return 1.0f / (1.0f + __expf(-x));
}

// Counted-vmcnt barrier pair (T3/T4 pattern, m201/m218 template):
// ACQ(N): next-tile loads stay in flight (vmcnt(N)), current tile published.
// REL: plain execution barrier, no drain.
#define BAR_ACQ(N) do { \
    asm volatile("s_waitcnt vmcnt(" #N ")" ::: "memory"); \
    __builtin_amdgcn_s_barrier(); \
    __builtin_amdgcn_sched_barrier(0); } while (0)
#define BAR_REL() do { \
    __builtin_amdgcn_sched_barrier(0); \
    __builtin_amdgcn_s_barrier(); } while (0)

// ---------------------------------------------------------------------------
// k_fsum: fused sigmoid + symmetrize + degree-normalize, one block per batch.
// S = sigmoid(z_b) lives ONLY in LDS (256 x LD f16); row sums via shuffle,
// col sums via per-lane partials + cross-wave LDS reduce; then
// nA[i,j] = (0.5*(S_ij+S_ji)+delta_ij)*Di*Dj emitted straight to global.
// LD=258: rows are 516 B (4B-aligned only!) -> all LDS accesses to T <=4B.
__global__ __launch_bounds__(512) void k_fsum(const float* __restrict__ z,
                                              f16* __restrict__ nA) {
    constexpr int LD = 258;
    __shared__ f16 T[256 * LD];          // 132,096 B
    __shared__ float cpart[8][256];      // 8 KB
    __shared__ float rbuf[256];
    __shared__ float Dv[256];

    const int b = blockIdx.x;
    const int tid = threadIdx.x, lane = tid & 63, w = tid >> 6;
    const float* zb = z + (size_t)b * (N_ * N_);

    float colacc[4] = {0.f, 0.f, 0.f, 0.f};
    for (int r = 0; r < 32; r++) {
        int i = w * 32 + r;
        float4 v = *(const float4*)(zb + (size_t)i * N_ + lane * 4);
        float s0 = sigmoidf_(v.x), s1 = sigmoidf_(v.y),
              s2 = sigmoidf_(v.z), s3 = sigmoidf_(v.w);
        f16x2 p0 = { (f16)s0, (f16)s1 }, p1 = { (f16)s2, (f16)s3 };
        *(f16x2*)&T[i * LD + lane * 4]     = p0;   // byte 516*i + 8*lane: 4B-aligned
        *(f16x2*)&T[i * LD + lane * 4 + 2] = p1;
        colacc[0] += s0; colacc[1] += s1; colacc[2] += s2; colacc[3] += s3;
        float rs = s0 + s1 + s2 + s3;
        for (int off = 32; off; off >>= 1) rs += __shfl_down(rs, off, 64);
        if (lane == 0) rbuf[i] = rs;
    }
    #pragma unroll
    for (int k = 0; k < 4; k++) cpart[w][lane * 4 + k] = colacc[k];
    __syncthreads();

    if (tid < 256) {
        float cs = 0.f;
        #pragma unroll
        for (int ww = 0; ww < 8; ww++) cs += cpart[ww][tid];
        Dv[tid] = rsqrtf(1.0f + 1e-6f + 0.5f * (rbuf[tid] + cs));
    }
    __syncthreads();

    // emit: each thread owns column-chunk j8 = (tid&31)*8 across 16 rows.
    const int j8 = (tid & 31) * 8;
    float dj[8];
    #pragma unroll
    for (int k = 0; k < 8; k++) dj[k] = Dv[j8 + k];
    f16* Ob = nA + (size_t)b * (N_ * N_);
    for (int it = 0; it < 16; it++) {
        int i = it * 16 + (tid >> 5);
        float di = Dv[i];
        // direct row read as 4 x f16x2 (4B-aligned; b128 would fault on odd i)
        f16x2 dd[4];
        #pragma unroll
        for (int c = 0; c < 4; c++)
            dd[c] = *(const f16x2*)&T[i * LD + j8 + c * 2];
        f16x8 o;
        #pragma unroll
        for (int k = 0; k < 8; k++) {
            float sij = (float)dd[k >> 1][k & 1];
            float v = 0.5f * (sij + (float)T[(j8 + k) * LD + i]);
            if (i == j8 + k) v += 1.0f;
            o[k] = (f16)(v * di * dj[k]);
        }
        *(f16x8*)&Ob[(size_t)i * N_ + j8] = o;     // global 16B store, aligned
    }
}

// ---------------------------------------------------------------------------
// k_prep: fused weight preprocessing.
// blocks [0,512): XW1t[h,node] = ne[node]·w1[:,h] + b1[h]
// blocks [512,2560): w{2,3}t transpose to f16.
__global__ __launch_bounds__(256) void k_prep(const float* __restrict__ ne,
                                              const float* __restrict__ w1,
                                              const float* __restrict__ b1,
                                              const float* __restrict__ w2,
                                              const float* __restrict__ w3,
                                              f16* __restrict__ XW1t,
                                              f16* __restrict__ w2t,
                                              f16* __restrict__ w3t) {
    int bid = blockIdx.x;
    if (bid < 512) {
        int h = bid, node = threadIdx.x;
        float s = b1[h];
        #pragma unroll 8
        for (int k = 0; k < F_; k++) s += ne[node * F_ + k] * w1[k * H_ + h];
        XW1t[h * N_ + node] = (f16)s;
    } else {
        int idx4 = bid - 512;                    // 0..2047
        int which = idx4 >> 10;                  // 0 -> w2, 1 -> w3
        const float* src = which ? w3 : w2;
        f16* dst = which ? w3t : w2t;
        int idx = (idx4 & 1023) * 256 + threadIdx.x;   // 0..262143
        int k = idx >> 9, n = idx & 511;
        dst[n * H_ + k] = (f16)src[k * H_ + n];
    }
}

// ---------------------------------------------------------------------------
// k_gemm: C(128x128) = A(m,K) @ Bt(n,K)^T. Used only for layer 1 now.
// MODE 0: Out[b][node][512] = relu(acc)
template <int KDIM, int MODE>
__global__ __launch_bounds__(256, 4) void k_gemm(const f16* __restrict__ A, long aBatch,
                                                 const f16* __restrict__ Bt, long bBatch,
                                                 f16* __restrict__ Out,
                                                 const float* __restrict__ bias,
                                                 float* __restrict__ gp) {
    __shared__ f16 As[128 * 64];
    __shared__ f16 Bs[128 * 64];
    const int tid  = threadIdx.x;
    const int lane = tid & 63, wave = tid >> 6;
    const int wm = wave >> 1, wn = wave & 1;

    const int lin = blockIdx.x;
    const int xcd = lin & 7, q = lin >> 3;
    const int n_t = q & 3, p = q >> 2;
    const int grp = xcd * 64 + p;          // 0..511 = (b, m-tile)
    const int b   = grp >> 1, m_t = grp & 1;
    const int m0 = m_t * 128, n0 = n_t * 128;

    const f16* Ab = A + (size_t)b * aBatch;
    const f16* Bb = Bt + (size_t)b * bBatch;

    f32x4 acc[4][4];
    #pragma unroll
    for (int i = 0; i < 4; i++)
        #pragma unroll
        for (int j = 0; j < 4; j++)
            #pragma unroll
            for (int r = 0; r < 4; r++) acc[i][j][r] = 0.0f;

    const int lr = lane >> 3;              // 0..7 row within chunk
    const int kc = (lane & 7) ^ lr;        // global 16B k-chunk to fetch

    const int ln15 = lane & 15;

    for (int kk = 0; kk < KDIM; kk += 64) {
        #pragma unroll
        for (int c = 0; c < 4; c++) {
            int chunk = wave * 4 + c;      // 0..15
            int row = chunk * 8 + lr;      // 0..127
            __builtin_amdgcn_global_load_lds(
                (__attribute__((address_space(1))) void*)(Ab + (size_t)(m0 + row) * KDIM + kk + kc * 8),
                (__attribute__((address_space(3))) void*)(&As[chunk * 512]), 16, 0, 0);
            __builtin_amdgcn_global_load_lds(
                (__attribute__((address_space(1))) void*)(Bb + (size_t)(n0 + row) * KDIM + kk + kc * 8),
                (__attribute__((address_space(3))) void*)(&Bs[chunk * 512]), 16, 0, 0);
        }
        __syncthreads();

        #pragma unroll
        for (int ks = 0; ks < 2; ks++) {
            const int rkc = ks * 4 + (lane >> 4);
            f16x8 aF[4];
            #pragma unroll
            for (int t = 0; t < 4; t++) {
                int ra = wm * 64 + t * 16 + ln15;
                aF[t] = *(const f16x8*)&As[(ra * 8 + (rkc ^ (ra & 7))) * 8];
            }
            #pragma unroll
            for (int h2 = 0; h2 < 2; h2++) {
                f16x8 bF[2];
                #pragma unroll
                for (int t = 0; t < 2; t++) {
                    int rb = wn * 64 + (h2 * 2 + t) * 16 + ln15;
                    bF[t] = *(const f16x8*)&Bs[(rb * 8 + (rkc ^ (rb & 7))) * 8];
                }
                #pragma unroll
                for (int mt = 0; mt < 4; mt++)
                    #pragma unroll
                    for (int t = 0; t < 2; t++)
                        acc[mt][h2 * 2 + t] = __builtin_amdgcn_mfma_f32_16x16x32_f16(aF[mt], bF[t], acc[mt][h2 * 2 + t], 0, 0, 0);
            }
        }
        __syncthreads();
    }

    const int quad = lane >> 4;
    if (MODE == 0) {
        f16* Ob = Out + (size_t)b * (N_ * H_);
        #pragma unroll
        for (int mt = 0; mt < 4; mt++) {
            int node = m0 + wm * 64 + mt * 16 + quad * 4;
            #pragma unroll
            for (int nt = 0; nt < 4; nt++) {
                int h = n0 + wn * 64 + nt * 16 + ln15;
                #pragma unroll
                for (int rr = 0; rr < 4; rr++) {
                    float v = acc[mt][nt][rr];
                    v = v > 0.f ? v : 0.f;
                    Ob[(size_t)(node + rr) * H_ + h] = (f16)v;
                }
            }
        }
    }
}

// ---------------------------------------------------------------------------
// k_fused v3: round-1 dataflow + counted-vmcnt schedule (T3/T4/T5).
//   stage 1: U[j,h] = Hin_b[j,:] @ Wt[hc*128+h,:]^T + bias[h]   (256x128, K=512)
//            -> kept in LDS as U_t[h][j] (f16, XOR-chunk swizzled)
//   stage 2: relu(nA_b @ U)  (256x128, K=256), B-operand straight from LDS.
// Barriers never drain vmcnt to 0 in the main loops: per wave, stage1 issues
// 6 gload_lds / K-step, stage2 issues 4 -> s_waitcnt vmcnt(6|4) before the
// acquire barrier keeps the next tile's loads in flight (m218 pattern).
// REDUCE=0: write Hout[b][node][512] node-major.
// REDUCE=1: node-sum readout -> gp[b][512].
template <int REDUCE>
__global__ __launch_bounds__(512, 2) void k_fused(const f16* __restrict__ Hin,
                                                  const f16* __restrict__ Wt,
                                                  const float* __restrict__ bias,
                                                  const f16* __restrict__ nA,
                                                  f16* __restrict__ Hout,
                                                  float* __restrict__ gp) {
    __shared__ f16 As[2][16384];   // 2 x (256 rows x 64 f16) = 64 KB
    __shared__ f16 WU[32768];      // stage1: Ws[2][8192] (2x16KB); stage2: U_t 128x256

    const int tid  = threadIdx.x;
    const int lane = tid & 63, wave = tid >> 6;
    const int ln15 = lane & 15, quad = lane >> 4;
    const int wm = wave >> 1, wn = wave & 1;     // wm: m-quadrant(4), wn: n-half(2)

    // XCD grouping: 4 hc-blocks of one batch land on one XCD (share Hin_b, nA_b in L2)
    const int lin = blockIdx.x;
    const int xcd = lin & 7, p = lin >> 3;
    const int grp = xcd * 128 + p;               // 0..1023
    const int b = grp >> 2, hc = grp & 3;

    const f16* Hb = Hin + (size_t)b * (N_ * H_);
    const f16* Ab = nA + (size_t)b * (N_ * N_);
    const f16* Wc = Wt + (size_t)(hc * 128) * H_;

    const int lr = lane >> 3;
    const int kc = (lane & 7) ^ lr;              // swizzled global 16B k-chunk

    // loaders: chunk = 8 rows x 64 f16 = 1 KB; LDS slot s of row r holds global chunk s^(r&7)
    auto stage1 = [&](int buf, int kt) {         // 6 gload_lds per wave
        #pragma unroll
        for (int c = 0; c < 4; c++) {            // Hin: 32 chunks / 8 waves
            int chunk = wave * 4 + c;
            int row = chunk * 8 + lr;            // 0..255
            __builtin_amdgcn_global_load_lds(
                (__attribute__((address_space(1))) void*)(Hb + (size_t)row * H_ + kt * 64 + kc * 8),
                (__attribute__((address_space(3))) void*)(&As[buf][chunk * 512]), 16, 0, 0);
        }
        #pragma unroll
        for (int c = 0; c < 2; c++) {            // Wt: 16 chunks / 8 waves
            int chunk = wave * 2 + c;
            int row = chunk * 8 + lr;            // 0..127
            __builtin_amdgcn_global_load_lds(
                (__attribute__((address_space(1))) void*)(Wc + (size_t)row * H_ + kt * 64 + kc * 8),
                (__attribute__((address_space(3))) void*)(&WU[buf * 8192 + chunk * 512]), 16, 0, 0);
        }
    };
    auto stage2 = [&](int buf, int jt) {         // 4 gload_lds per wave
        #pragma unroll
        for (int c = 0; c < 4; c++) {            // nA: 32 chunks / 8 waves
            int chunk = wave * 4 + c;
            int row = chunk * 8 + lr;
            __builtin_amdgcn_global_load_lds(
                (__attribute__((address_space(1))) void*)(Ab + (size_t)row * N_ + jt * 64 + kc * 8),
                (__attribute__((address_space(3))) void*)(&As[buf][chunk * 512]), 16, 0, 0);
        }
    };

    f32x4 acc[4][4];
    #pragma unroll
    for (int i = 0; i < 4; i++)
        #pragma unroll
        for (int j = 0; j < 4; j++)
            #pragma unroll
            for (int r = 0; r < 4; r++) acc[i][j][r] = 0.0f;

    // ---------------- stage 1: U = Hin @ Wc^T + bias --------------------
    stage1(0, 0);                                // 6 loads in flight; no drain
    for (int kt = 0; kt < 8; ++kt) {
        const int buf = kt & 1;
        if (kt < 7) {
            stage1(buf ^ 1, kt + 1);             // +6 (12 in flight)
            BAR_ACQ(6);                          // oldest 6 (tile kt) landed
        } else {
            stage2(0, 0);                        // +4: prefetch first nA tile
            BAR_ACQ(4);                          // oldest 6 (tile 7) landed
        }
        __builtin_amdgcn_s_setprio(1);
        #pragma unroll
        for (int ks = 0; ks < 2; ks++) {
            const int rkc = ks * 4 + quad;
            f16x8 aF[4], bF[4];
            #pragma unroll
            for (int t = 0; t < 4; t++) {
                int ra = wm * 64 + t * 16 + ln15;          // Hin row (j)
                aF[t] = *(const f16x8*)&As[buf][(ra * 8 + (rkc ^ (ra & 7))) * 8];
            }
            #pragma unroll
            for (int t = 0; t < 4; t++) {
                int rb = wn * 64 + t * 16 + ln15;          // Wt row (h), 0..127
                bF[t] = *(const f16x8*)&WU[buf * 8192 + (rb * 8 + (rkc ^ (rb & 7))) * 8];
            }
            #pragma unroll
            for (int mt = 0; mt < 4; mt++)
                #pragma unroll
                for (int nt = 0; nt < 4; nt++)
                    acc[mt][nt] = __builtin_amdgcn_mfma_f32_16x16x32_f16(aF[mt], bF[nt], acc[mt][nt], 0, 0, 0);
        }
        __builtin_amdgcn_s_setprio(0);
        BAR_REL();                               // no drain: prefetch stays in flight
    }

    // epilogue 1: acc(+bias) -> U_t[h][j] in WU, chunk-swizzled.
    // C layout: m(j) = wm*64+mt*16+quad*4+rr (4 consecutive j -> f16x4), n(h) = wn*64+nt*16+ln15
    #pragma unroll
    for (int nt = 0; nt < 4; nt++) {
        int hl = wn * 64 + nt * 16 + ln15;
        float bv = bias[hc * 128 + hl];
        #pragma unroll
        for (int mt = 0; mt < 4; mt++) {
            int j = wm * 64 + mt * 16 + quad * 4;
            int slot = (j >> 3) ^ (hl & 7);
            f16x4 v;
            #pragma unroll
            for (int rr = 0; rr < 4; rr++) v[rr] = (f16)(acc[mt][nt][rr] + bv);
            *(f16x4*)&WU[hl * 256 + slot * 8 + (j & 7)] = v;
        }
    }
    // publish U_t: drain own LDS writes, then barrier (vmcnt stays 4: jt=0 prefetch)
    asm volatile("s_waitcnt lgkmcnt(0)" ::: "memory");
    __builtin_amdgcn_s_barrier();
    __builtin_amdgcn_sched_barrier(0);

    // ---------------- stage 2: relu(nA @ U) -----------------------------
    #pragma unroll
    for (int i = 0; i < 4; i++)
        #pragma unroll
        for (int j = 0; j < 4; j++)
            #pragma unroll
            for (int r = 0; r < 4; r++) acc[i][j][r] = 0.0f;

    for (int jt = 0; jt < 4; ++jt) {
        const int buf = jt & 1;
        if (jt < 3) {
            stage2(buf ^ 1, jt + 1);             // +4 (8 in flight)
            BAR_ACQ(4);                          // oldest 4 (tile jt) landed
        } else {
            BAR_ACQ(0);                          // last tile: drain remaining
        }
        __builtin_amdgcn_s_setprio(1);
        #pragma unroll
        for (int ks = 0; ks < 2; ks++) {
            const int rkc = ks * 4 + quad;
            f16x8 aF[4], bF[4];
            #pragma unroll
            for (int t = 0; t < 4; t++) {
                int ra = wm * 64 + t * 16 + ln15;          // nA row (i)
                aF[t] = *(const f16x8*)&As[buf][(ra * 8 + (rkc ^ (ra & 7))) * 8];
            }
            #pragma unroll
            for (int t = 0; t < 4; t++) {
                int rb = wn * 64 + t * 16 + ln15;          // U_t row (h), 0..127
                int g = jt * 8 + rkc;                      // global 8-f16 chunk in row
                bF[t] = *(const f16x8*)&WU[rb * 256 + ((g ^ (rb & 7)) * 8)];
            }
            #pragma unroll
            for (int mt = 0; mt < 4; mt++)
                #pragma unroll
                for (int nt = 0; nt < 4; nt++)
                    acc[mt][nt] = __builtin_amdgcn_mfma_f32_16x16x32_f16(aF[mt], bF[nt], acc[mt][nt], 0, 0, 0);
        }
        __builtin_amdgcn_s_setprio(0);
        BAR_REL();
    }

    if (REDUCE == 0) {
        f16* Ob = Hout + (size_t)b * (N_ * H_);
        #pragma unroll
        for (int mt = 0; mt < 4; mt++) {
            int node = wm * 64 + mt * 16 + quad * 4;
            #pragma unroll
            for (int nt = 0; nt < 4; nt++) {
                int hg = hc * 128 + wn * 64 + nt * 16 + ln15;
                #pragma unroll
                for (int rr = 0; rr < 4; rr++) {
                    float v = acc[mt][nt][rr];
                    v = v > 0.f ? v : 0.f;
                    Ob[(size_t)(node + rr) * H_ + hg] = (f16)v;
                }
            }
        }
    } else {
        // node-sum readout: this block covers ALL 256 nodes -> gp[b][hc*128 + c]
        float part[4];
        #pragma unroll
        for (int nt = 0; nt < 4; nt++) {
            float s = 0.f;
            #pragma unroll
            for (int mt = 0; mt < 4; mt++)
                #pragma unroll
                for (int rr = 0; rr < 4; rr++) {
                    float v = acc[mt][nt][rr];
                    s += (v > 0.f ? v : 0.f);
                }
            s += __shfl_down(s, 32, 64);
            s += __shfl_down(s, 16, 64);
            part[nt] = s;                        // valid on quad==0 lanes
        }
        __syncthreads();                         // LDS dead; reuse As as float scratch
        float* red = (float*)&As[0][0];          // 8 waves x 64 cols
        if (quad == 0) {
            #pragma unroll
            for (int nt = 0; nt < 4; nt++)
                red[wave * 64 + nt * 16 + ln15] = part[nt];
        }
        __syncthreads();
        if (tid < 128) {
            int wnl = tid >> 6, cl = tid & 63;
            float g = red[(0 * 2 + wnl) * 64 + cl] + red[(1 * 2 + wnl) * 64 + cl]
                    + red[(2 * 2 + wnl) * 64 + cl] + red[(3 * 2 + wnl) * 64 + cl];
            gp[(size_t)b * H_ + hc * 128 + tid] = g;
        }
    }
}

// ---------------------------------------------------------------------------
// k_logits: logits[b] = (gp[b]/N) @ fcw + fcb.  grid B_ x 256.
__global__ __launch_bounds__(256) void k_logits(const float* __restrict__ gp,
                                                const float* __restrict__ fcw,
                                                const float* __restrict__ fcb,
                                                float* __restrict__ out) {
    int b = blockIdx.x, tid = threadIdx.x;
    const float* g = gp + (size_t)b * H_;
    float g0 = g[tid];
    float g1 = g[tid + 256];
    float p0 = g0 * fcw[tid * 2 + 0] + g1 * fcw[(tid + 256) * 2 + 0];
    float p1 = g0 * fcw[tid * 2 + 1] + g1 * fcw[(tid + 256) * 2 + 1];
    for (int off = 32; off; off >>= 1) {
        p0 += __shfl_down(p0, off, 64);
        p1 += __shfl_down(p1, off, 64);
    }
    __shared__ float r0[4], r1[4];
    int lane = tid & 63, w = tid >> 6;
    if (lane == 0) { r0[w] = p0; r1[w] = p1; }
    __syncthreads();
    const float inv = 1.0f / N_;
    if (tid == 0) out[b * 2 + 0] = (r0[0] + r0[1] + r0[2] + r0[3]) * inv + fcb[0];
    if (tid == 1) out[b * 2 + 1] = (r1[0] + r1[1] + r1[2] + r1[3]) * inv + fcb[1];
}

// ---------------------------------------------------------------------------
extern "C" void kernel_launch(void* const* d_in, const int* in_sizes, int n_in,
                              void* d_out, int out_size, void* d_ws, size_t ws_size,
                              hipStream_t stream) {
    const float* z   = (const float*)d_in[0];
    const float* ne  = (const float*)d_in[1];
    const float* w1  = (const float*)d_in[2];
    const float* b1  = (const float*)d_in[3];
    const float* w2  = (const float*)d_in[4];
    const float* b2  = (const float*)d_in[5];
    const float* w3  = (const float*)d_in[6];
    const float* b3  = (const float*)d_in[7];
    const float* fcw = (const float*)d_in[8];
    const float* fcb = (const float*)d_in[9];
    float* out = (float*)d_out;

    char* ws = (char*)d_ws;
    f16*   T     = (f16*)(ws + 0);            // 67,108,864 (T2/T3 intermediate)
    f16*   nA    = (f16*)(ws + 67108864);     // 33,554,432
    f16*   Hh    = (f16*)(ws + 100663296);    // 67,108,864 (H1)
    float* gpart = (float*)(ws + 100663296);  //    524,288 (alias Hh, H1 dead after F2)
    f16*   XW1t  = (f16*)(ws + 167772160);    //    262,144
    f16*   w2t   = (f16*)(ws + 168034304);    //    524,288
    f16*   w3t   = (f16*)(ws + 168558592);    //    524,288

    // Fused sigmoid/symmetrize/normalize: z -> nA directly (S never hits HBM)
    k_fsum<<<256, 512, 0, stream>>>(z, nA);
    k_prep<<<2560, 256, 0, stream>>>(ne, w1, b1, w2, w3, XW1t, w2t, w3t);

    // Layer 1: H1 = relu(nA @ XW1)
    k_gemm<256, 0><<<2048, 256, 0, stream>>>(nA, 65536, XW1t, 0, Hh, nullptr, nullptr);
    // Layer 2 fused: H2 = relu(nA @ (H1 @ w2 + b2))   (U never touches HBM)
    k_fused<0><<<1024, 512, 0, stream>>>(Hh, w2t, b2, nA, T, nullptr);
    // Layer 3 fused + readout: gp[b][h] = sum_i relu(nA @ (H2 @ w3 + b3))[i][h]
    k_fused<1><<<1024, 512, 0, stream>>>(T, w3t, b3, nA, nullptr, gpart);

    k_logits<<<B_, 256, 0, stream>>>(gpart, fcw, fcb, out);
}